// Round 10
// baseline (505.071 us; speedup 1.0000x reference)
//
#include <hip/hip_runtime.h>

typedef __bf16 bf16x8 __attribute__((ext_vector_type(8)));
typedef __bf16 bf16x2_t __attribute__((ext_vector_type(2)));
typedef float f32x4 __attribute__((ext_vector_type(4)));
typedef float f32x16 __attribute__((ext_vector_type(16)));
typedef unsigned int u32x4 __attribute__((ext_vector_type(4)));
typedef unsigned short u16x8 __attribute__((ext_vector_type(8)));

#define EMB 2048
#define NH 16
#define HD 128
#define TSEQ 4096

// ---------- helpers ----------
__device__ __forceinline__ unsigned short f2bf(float x) {
  unsigned int u = __builtin_bit_cast(unsigned int, x);
  u += 0x7fffu + ((u >> 16) & 1u);   // RNE
  return (unsigned short)(u >> 16);
}

__device__ __forceinline__ float bf2f(unsigned short u) {
  unsigned int x = ((unsigned int)u) << 16;
  return __builtin_bit_cast(float, x);
}

__device__ __forceinline__ float ex2(float x) { return __builtin_amdgcn_exp2f(x); }

__device__ __forceinline__ void gl_lds16(const void* g, void* l) {
  __builtin_amdgcn_global_load_lds((__attribute__((address_space(1))) void*)(void*)g,
                                   (__attribute__((address_space(3))) void*)l, 16, 0, 0);
}

template <typename OutT>
__device__ __forceinline__ void store_out(OutT* p, float v) {
  if constexpr (sizeof(OutT) == 2) { *p = f2bf(v); } else { *p = v; }
}

// ---------- fused fp32 -> bf16 convert for all 7 tensors ----------
__global__ __launch_bounds__(256) void cvt_all(const float* __restrict__ q, const float* __restrict__ k,
                                               const float* __restrict__ v, const float* __restrict__ Wq,
                                               const float* __restrict__ Wk, const float* __restrict__ Wv,
                                               const float* __restrict__ Wo,
                                               unsigned short* qb, unsigned short* kb, unsigned short* vb,
                                               unsigned short* Wqb, unsigned short* Wkb, unsigned short* Wvb,
                                               unsigned short* Wob) {
  const int SX = TSEQ * EMB / 8;   // 2^20
  const int SW = EMB * EMB / 8;    // 2^19
  int i = blockIdx.x * 256 + threadIdx.x;
  const float* src; unsigned short* dst; int off;
  if (i < 3 * SX) {
    int seg = i >> 20; off = i & (SX - 1);
    src = (seg == 0) ? q : (seg == 1) ? k : v;
    dst = (seg == 0) ? qb : (seg == 1) ? kb : vb;
  } else {
    int j = i - 3 * SX;
    int seg = j >> 19; off = j & (SW - 1);
    src = (seg == 0) ? Wq : (seg == 1) ? Wk : (seg == 2) ? Wv : Wo;
    dst = (seg == 0) ? Wqb : (seg == 1) ? Wkb : (seg == 2) ? Wvb : Wob;
  }
  const float4* p = (const float4*)src + (size_t)off * 2;
  float4 a = p[0], b = p[1];
  u32x4 r;
  r.x = (unsigned)f2bf(a.x) | ((unsigned)f2bf(a.y) << 16);
  r.y = (unsigned)f2bf(a.z) | ((unsigned)f2bf(a.w) << 16);
  r.z = (unsigned)f2bf(b.x) | ((unsigned)f2bf(b.y) << 16);
  r.w = (unsigned)f2bf(b.z) | ((unsigned)f2bf(b.w) << 16);
  ((u32x4*)dst)[off] = r;
}

// ================= 256x256 deep-pipelined NT GEMM: C = A[M,K] * B[N,K]^T =================
// BK=64, 512 threads = 8 waves (2 wr x 4 wc), per-wave 128x64 output, 16x16x32 MFMA.
// LDS 128 KB: bufA[2]=[256][128B] @0/32K, bufB[2] @64K/96K; XOR swizzle byte^=(row&7)<<4
// on BOTH sides (pre-swizzled global source, linear gl_lds dest; swizzled ds_read).
// 4 phases per K-tile (mh,ks); B-frags reg-reused across mh (24 ds_read_b128/tile/wave).
// Staging ledger (1 row-half = 2 loads/thread per phase):
//   ph0: A-h0(t+1) -> bufA[d^1] (released end-ph3(t-1));  ph1: A-h1(t+1)
//   ph2: B-h0(t+2) -> bufB[d]   (B reads done end-ph1(t)); ph3: B-h1(t+2)
// One fence per K-tile at end-ph3: vmcnt(4) leaves exactly B(t+2) in flight.
// All prefetch leads >= 4 phases (~2000 cyc) >> L2 latency.

__device__ __forceinline__ void g256_stage(const char* gbase, char* dstBase, int t, int half,
                                           int tt, int K) {
#pragma unroll
  for (int j = 0; j < 2; j++) {
    const int rl = half * 128 + (t >> 3) + j * 64;      // row within 256-row tile
    const int cb = (t & 7) * 16;                        // colbyte within 128B row
    const char* src = gbase + (size_t)rl * (K * 2) + (size_t)tt * 128 + (cb ^ ((rl & 7) << 4));
    gl_lds16(src, dstBase + rl * 128 + cb);             // linear dest = waveBase + lane*16
  }
}

template <typename OutT>
__device__ __forceinline__ void gemm256_body(const unsigned short* __restrict__ A,
                                             const unsigned short* __restrict__ B,
                                             OutT* __restrict__ C,
                                             int m0, int n0, int N, int K, char* sm, float oscale) {
  const int t = threadIdx.x;
  const int l = t & 63;
  const int wv = t >> 6;
  const int wr = wv >> 2, wc = wv & 3;
  const int l15 = l & 15, lg = l >> 4;

  f32x4 acc[2][4][4] = {};   // [mh][mf][nf]

  const char* Ag = (const char*)A + (size_t)m0 * (K * 2);
  const char* Bg = (const char*)B + (size_t)n0 * (K * 2);
  char* bufA[2] = {sm, sm + 32768};
  char* bufB[2] = {sm + 65536, sm + 98304};

  const int NT = K / 64;   // 32

  // prologue: A(0) h0,h1; B(0) h0,h1; B(1) h0,h1  (12 loads)
  g256_stage(Ag, bufA[0], t, 0, 0, K);
  g256_stage(Ag, bufA[0], t, 1, 0, K);
  g256_stage(Bg, bufB[0], t, 0, 0, K);
  g256_stage(Bg, bufB[0], t, 1, 0, K);
  g256_stage(Bg, bufB[1], t, 0, 1, K);
  g256_stage(Bg, bufB[1], t, 1, 1, K);
  asm volatile("s_waitcnt vmcnt(4)" ::: "memory");   // tile0 A+B landed; B(1) in flight
  __builtin_amdgcn_s_barrier();

  for (int tt = 0; tt < NT; ++tt) {
    const int d = tt & 1;
    char* cA = bufA[d];
    char* cB = bufB[d];
    bf16x8 bfr[2][4];   // [ks][nf], loaded ph0/ph1, reused ph2/ph3
#pragma unroll
    for (int ph = 0; ph < 4; ++ph) {
      const int mh = ph >> 1, ks = ph & 1;
      // ds reads (this quadrant's A; B only on mh==0)
      bf16x8 afr[4];
#pragma unroll
      for (int mf = 0; mf < 4; mf++) {
        const int r = wr * 128 + mh * 64 + mf * 16 + l15;
        afr[mf] = *(const bf16x8*)(cA + r * 128 + ((ks * 64 + lg * 16) ^ ((r & 7) << 4)));
      }
      if (mh == 0) {
#pragma unroll
        for (int nf = 0; nf < 4; nf++) {
          const int r = wc * 64 + nf * 16 + l15;
          bfr[ks][nf] = *(const bf16x8*)(cB + r * 128 + ((ks * 64 + lg * 16) ^ ((r & 7) << 4)));
        }
      }
      // staging (see ledger above)
      if (ph == 0 && tt + 1 < NT) g256_stage(Ag, bufA[d ^ 1], t, 0, tt + 1, K);
      if (ph == 1 && tt + 1 < NT) g256_stage(Ag, bufA[d ^ 1], t, 1, tt + 1, K);
      if (ph == 2 && tt + 2 < NT) g256_stage(Bg, cB, t, 0, tt + 2, K);
      if (ph == 3 && tt + 2 < NT) g256_stage(Bg, cB, t, 1, tt + 2, K);

      __builtin_amdgcn_s_barrier();
      __builtin_amdgcn_s_setprio(1);
#pragma unroll
      for (int mf = 0; mf < 4; mf++)
#pragma unroll
        for (int nf = 0; nf < 4; nf++)
          acc[mh][mf][nf] = __builtin_amdgcn_mfma_f32_16x16x32_bf16(afr[mf], bfr[ks][nf],
                                                                    acc[mh][mf][nf], 0, 0, 0);
      __builtin_amdgcn_s_setprio(0);
      if (ph == 3) {
        if (tt + 2 < NT) asm volatile("s_waitcnt vmcnt(4)" ::: "memory");  // A(t+1),B(t+1) landed
        else             asm volatile("s_waitcnt vmcnt(0)" ::: "memory");  // tail drain
      }
      __builtin_amdgcn_s_barrier();
    }
  }

#pragma unroll
  for (int mh = 0; mh < 2; mh++)
#pragma unroll
    for (int mf = 0; mf < 4; mf++)
#pragma unroll
      for (int nf = 0; nf < 4; nf++) {
        const int col = n0 + wc * 64 + nf * 16 + l15;
        const int rb = m0 + wr * 128 + mh * 64 + mf * 16 + 4 * lg;
#pragma unroll
        for (int i = 0; i < 4; i++)
          store_out(C + (size_t)(rb + i) * N + col, acc[mh][mf][nf][i] * oscale);
      }
}

// Fused Q/K/V projections: 384 blocks (3 GEMMs x 128 tiles), XCD-bijective (384%8==0).
// Q pre-scaled by 1/sqrt(HD)*log2(e) for exp2-domain softmax.
__global__ __launch_bounds__(512) void gemm_qkv(const unsigned short* __restrict__ qb,
                                                const unsigned short* __restrict__ kb,
                                                const unsigned short* __restrict__ vb,
                                                const unsigned short* __restrict__ Wq,
                                                const unsigned short* __restrict__ Wk,
                                                const unsigned short* __restrict__ Wv,
                                                unsigned short* Qo, unsigned short* Ko,
                                                unsigned short* Vto) {
  __shared__ char sm[131072];
  const int bid = blockIdx.x;
  const int wg = (bid & 7) * 48 + (bid >> 3);
  const int z = wg >> 7, r = wg & 127;
  const unsigned short *A, *B; unsigned short* C;
  int m0, n0, N; float sc;
  if (z == 0)      { A = qb; B = Wq; C = Qo;  m0 = (r >> 3) * 256; n0 = (r & 7) * 256;  N = EMB;  sc = 0.12751743f; }
  else if (z == 1) { A = kb; B = Wk; C = Ko;  m0 = (r >> 3) * 256; n0 = (r & 7) * 256;  N = EMB;  sc = 1.0f; }
  else             { A = Wv; B = vb; C = Vto; m0 = (r >> 4) * 256; n0 = (r & 15) * 256; N = TSEQ; sc = 1.0f; }
  gemm256_body<unsigned short>(A, B, C, m0, n0, N, EMB, sm, sc);
}

__global__ __launch_bounds__(512) void gemm_o(const unsigned short* __restrict__ A,
                                              const unsigned short* __restrict__ B,
                                              float* __restrict__ C) {
  __shared__ char sm[131072];
  const int bid = blockIdx.x;
  const int wg = (bid & 7) * 16 + (bid >> 3);   // 128 blocks
  gemm256_body<float>(A, B, C, (wg >> 3) * 256, (wg & 7) * 256, EMB, EMB, sm, 1.0f);
}

// ---------- flash attention (causal), swapped-QK^T, 32x32x16 MFMA, static-max softmax ----------
// 512 UNIFORM blocks of exactly 33 kv-iterations each (kv-split pairing, see r5).
__global__ __launch_bounds__(256, 2) void attn_kernel(const unsigned short* __restrict__ Q,
                                                      const unsigned short* __restrict__ Kp,
                                                      const unsigned short* __restrict__ Vt,
                                                      unsigned short* __restrict__ slots,
                                                      float* __restrict__ lbuf) {
  __shared__ char sK[2][16384];  // [64 kv][128 hd] bf16, 256B rows, xor-swz (&15)
  __shared__ char sV[3][16384];  // [128 hd][64 kv] bf16, 128B rows, xor-swz (&7)
  const int t = threadIdx.x, l = t & 63, w = t >> 6;
  const int l31 = l & 31, hh = l >> 5;
  const int b = blockIdx.x;
  const int h = b >> 5;
  const int p = (b >> 1) & 15;
  const int half = b & 1;
  const int slotBase = (h * 16 + p) * 3;

  const int q0A = 128 * p, q0B = 128 * (31 - p);
  const int swi = (half == 0) ? (2 * p + 2) : 64;   // gi at which tile B starts (64 = never)
  const int kvOff = 31 - 2 * p;                     // half-1 kv-block offset

  int q0 = (half == 0) ? q0A : q0B;
  int qrow = q0 + w * 32 + l31;

  auto kvof = [&](int gi) -> int {
    if (half == 0) return (gi < swi) ? gi * 64 : (gi - swi) * 64;
    return (kvOff + gi) * 64;
  };

  bf16x8 qf[8];
#pragma unroll
  for (int kd = 0; kd < 8; kd++)
    qf[kd] = *(const bf16x8*)(Q + (size_t)qrow * EMB + h * HD + kd * 16 + hh * 8);

  f32x16 o[4] = {};
  float l_run = 0.0f;

  const int rK = t >> 4, cK = (t & 15) * 16;
  const int rV = t >> 3, cV = (t & 7) * 16;
  const char* Kb = (const char*)Kp;
  const char* Vb = (const char*)Vt;

  auto stage = [&](int kbuf, int vbuf, int kv0) {
#pragma unroll
    for (int c = 0; c < 4; c++) {
      int rowK = c * 16 + rK;
      gl_lds16(Kb + (size_t)(kv0 + rowK) * (EMB * 2) + h * (HD * 2) + (cK ^ ((rowK & 15) << 4)),
               sK[kbuf] + c * 4096 + t * 16);
      int rowV = c * 32 + rV;
      gl_lds16(Vb + (size_t)(h * HD + rowV) * (TSEQ * 2) + kv0 * 2 + (cV ^ ((rowV & 7) << 4)),
               sV[vbuf] + c * 4096 + t * 16);
    }
  };

  auto writeout = [&](int slotId) {
    unsigned short* S = slots + (size_t)slotId * (128 * 128);
    const int r = w * 32 + l31;
    float lt = l_run + __shfl_xor(l_run, 32, 64);
    if (hh == 0) lbuf[slotId * 128 + r] = lt;
#pragma unroll
    for (int hdm = 0; hdm < 4; hdm++)
#pragma unroll
      for (int rq = 0; rq < 4; rq++) {
        ushort4 st;
        st.x = f2bf(o[hdm][4 * rq + 0]);
        st.y = f2bf(o[hdm][4 * rq + 1]);
        st.z = f2bf(o[hdm][4 * rq + 2]);
        st.w = f2bf(o[hdm][4 * rq + 3]);
        *(ushort4*)(S + r * 128 + hdm * 32 + 8 * rq + 4 * hh) = st;
      }
  };

  stage(0, 0, kvof(0));
  int kc = 0, vc = 0, vn = 1;
  for (int gi = 0; gi < 33; ++gi) {
    if (half == 0 && gi == swi) {
      writeout(slotBase + 0);
#pragma unroll
      for (int hdm = 0; hdm < 4; hdm++)
#pragma unroll
        for (int i = 0; i < 16; i++) o[hdm][i] = 0.0f;
      l_run = 0.0f;
      q0 = q0B;
      qrow = q0 + w * 32 + l31;
#pragma unroll
      for (int kd = 0; kd < 8; kd++)
        qf[kd] = *(const bf16x8*)(Q + (size_t)qrow * EMB + h * HD + kd * 16 + hh * 8);
    }
    const int kv0 = kvof(gi);
    if (gi + 1 < 33) {
      stage(kc ^ 1, vn, kvof(gi + 1));
      asm volatile("s_waitcnt vmcnt(8)" ::: "memory");
    } else {
      asm volatile("s_waitcnt vmcnt(0)" ::: "memory");
    }
    __builtin_amdgcn_s_barrier();

    const char* KB = sK[kc];
    const char* VB = sV[vc];

    f32x16 s[2];
#pragma unroll
    for (int i = 0; i < 16; i++) { s[0][i] = -8.0f; s[1][i] = -8.0f; }
    __builtin_amdgcn_s_setprio(1);
#pragma unroll
    for (int kvm = 0; kvm < 2; kvm++) {
      const int rowA = kvm * 32 + l31;
      const int swz = (rowA & 15) << 4;
#pragma unroll
      for (int kd = 0; kd < 8; kd++) {
        bf16x8 kf = *(const bf16x8*)(KB + rowA * 256 + ((kd * 32 + hh * 16) ^ swz));
        s[kvm] = __builtin_amdgcn_mfma_f32_32x32x16_bf16(kf, qf[kd], s[kvm], 0, 0, 0);
      }
    }
    __builtin_amdgcn_s_setprio(0);
    __builtin_amdgcn_s_barrier();

    const bool diag = (kv0 + 64 > q0);
    if (diag) {
#pragma unroll
      for (int kvm = 0; kvm < 2; kvm++)
#pragma unroll
        for (int i = 0; i < 16; i++)
          if (kv0 + kvm * 32 + (i & 3) + 8 * (i >> 2) + 4 * hh > qrow) s[kvm][i] = -1e30f;
    }
    float psum = 0.0f;
    unsigned int wb[16];
#pragma unroll
    for (int kvm = 0; kvm < 2; kvm++)
#pragma unroll
      for (int m = 0; m < 8; m++) {
        float p0 = ex2(s[kvm][2 * m + 0]);
        float p1 = ex2(s[kvm][2 * m + 1]);
        psum += p0 + p1;
        bf16x2_t pk; pk[0] = (__bf16)p0; pk[1] = (__bf16)p1;
        wb[kvm * 8 + m] = __builtin_bit_cast(unsigned int, pk);
      }
    l_run += psum;

    __builtin_amdgcn_s_setprio(1);
#pragma unroll
    for (int kvm = 0; kvm < 2; kvm++)
#pragma unroll
      for (int sx = 0; sx < 2; sx++) {
        const int base = kvm * 8 + 4 * sx;
        const unsigned int a0 = wb[base + 0], a1 = wb[base + 1];
        const unsigned int b0 = wb[base + 2], b1 = wb[base + 3];
        const unsigned int snd0 = hh ? a0 : b0;
        const unsigned int snd1 = hh ? a1 : b1;
        const unsigned int rcv0 = (unsigned int)__shfl_xor((int)snd0, 32, 64);
        const unsigned int rcv1 = (unsigned int)__shfl_xor((int)snd1, 32, 64);
        u32x4 pw;
        pw.x = hh ? rcv0 : a0;
        pw.y = hh ? rcv1 : a1;
        pw.z = hh ? b0 : rcv0;
        pw.w = hh ? b1 : rcv1;
        const bf16x8 pfrag = __builtin_bit_cast(bf16x8, pw);
        const int ks = kvm * 2 + sx;
#pragma unroll
        for (int hdm = 0; hdm < 4; hdm++) {
          const int rowA = hdm * 32 + l31;
          bf16x8 vf = *(const bf16x8*)(VB + rowA * 128 + ((ks * 32 + hh * 16) ^ ((rowA & 7) << 4)));
          o[hdm] = __builtin_amdgcn_mfma_f32_32x32x16_bf16(vf, pfrag, o[hdm], 0, 0, 0);
        }
      }
    __builtin_amdgcn_s_setprio(0);

    kc ^= 1;
    vc = vn;
    vn = (vn == 2) ? 0 : vn + 1;
  }

  writeout(slotBase + ((half == 0) ? 1 : 2));
}

// ---------- merge partials -> normalized bf16 y ----------
__global__ __launch_bounds__(256) void merge_kernel(const unsigned short* __restrict__ slots,
                                                    const float* __restrict__ lbuf,
                                                    unsigned short* __restrict__ Y) {
  const int tile = blockIdx.x;
  const int h = tile >> 5, tt = tile & 31;
  const int p = (tt <= 15) ? tt : 31 - tt;
  const int base = (h * 16 + p) * 3;
  const int t = threadIdx.x;
  const int r = t >> 1;
  const int c0 = (t & 1) * 64;
  unsigned short* yp = Y + (size_t)(128 * tt + r) * EMB + h * HD + c0;
  if (tt <= 15) {
    const unsigned short* S = slots + (size_t)(base + 0) * (128 * 128) + r * 128 + c0;
    const float inv = 1.0f / lbuf[(base + 0) * 128 + r];
#pragma unroll
    for (int j = 0; j < 8; j++) {
      u16x8 a = ((const u16x8*)S)[j];
      u16x8 ov;
#pragma unroll
      for (int e = 0; e < 8; e++) ov[e] = f2bf(bf2f(a[e]) * inv);
      ((u16x8*)yp)[j] = ov;
    }
  } else {
    const unsigned short* S0 = slots + (size_t)(base + 1) * (128 * 128) + r * 128 + c0;
    const unsigned short* S1 = slots + (size_t)(base + 2) * (128 * 128) + r * 128 + c0;
    const float inv = 1.0f / (lbuf[(base + 1) * 128 + r] + lbuf[(base + 2) * 128 + r]);
#pragma unroll
    for (int j = 0; j < 8; j++) {
      u16x8 a = ((const u16x8*)S0)[j];
      u16x8 c = ((const u16x8*)S1)[j];
      u16x8 ov;
#pragma unroll
      for (int e = 0; e < 8; e++) ov[e] = f2bf((bf2f(a[e]) + bf2f(c[e])) * inv);
      ((u16x8*)yp)[j] = ov;
    }
  }
}

// ---------- residual + LayerNorm (scale only) ----------
__global__ __launch_bounds__(256) void ln_kernel(const float* __restrict__ y2,
                                                 const float* __restrict__ qin,
                                                 const float* __restrict__ lnw,
                                                 float* __restrict__ out) {
  const int row = blockIdx.x, t = threadIdx.x;
  const float4* Y = (const float4*)(y2 + (size_t)row * EMB);
  const float4* Qv = (const float4*)(qin + (size_t)row * EMB);
  float4 a = Y[t], b = Qv[t];
  float4 x0, x1;
  x0.x = a.x + b.x; x0.y = a.y + b.y; x0.z = a.z + b.z; x0.w = a.w + b.w;
  a = Y[t + 256]; b = Qv[t + 256];
  x1.x = a.x + b.x; x1.y = a.y + b.y; x1.z = a.z + b.z; x1.w = a.w + b.w;
  float s = x0.x + x0.y + x0.z + x0.w + x1.x + x1.y + x1.z + x1.w;
  float s2 = x0.x * x0.x + x0.y * x0.y + x0.z * x0.z + x0.w * x0.w +
             x1.x * x1.x + x1.y * x1.y + x1.z * x1.z + x1.w * x1.w;
#pragma unroll
  for (int d = 1; d < 64; d <<= 1) {
    s += __shfl_xor(s, d, 64);
    s2 += __shfl_xor(s2, d, 64);
  }
  __shared__ float red[8];
  if ((t & 63) == 0) { red[(t >> 6) * 2] = s; red[(t >> 6) * 2 + 1] = s2; }
  __syncthreads();
  s = red[0] + red[2] + red[4] + red[6];
  s2 = red[1] + red[3] + red[5] + red[7];
  float mu = s * (1.0f / EMB);
  float var = s2 * (1.0f / EMB) - mu * mu;
  float r = rsqrtf(var + 1e-5f);
  float4 w0 = ((const float4*)lnw)[t], w1 = ((const float4*)lnw)[t + 256];
  float4 o0, o1;
  o0.x = (x0.x - mu) * r * w0.x; o0.y = (x0.y - mu) * r * w0.y;
  o0.z = (x0.z - mu) * r * w0.z; o0.w = (x0.w - mu) * r * w0.w;
  o1.x = (x1.x - mu) * r * w1.x; o1.y = (x1.y - mu) * r * w1.y;
  o1.z = (x1.z - mu) * r * w1.z; o1.w = (x1.w - mu) * r * w1.w;
  ((float4*)(out + (size_t)row * EMB))[t] = o0;
  ((float4*)(out + (size_t)row * EMB))[t + 256] = o1;
}

// ---------- launch ----------
extern "C" void kernel_launch(void* const* d_in, const int* in_sizes, int n_in,
                              void* d_out, int out_size, void* d_ws, size_t ws_size,
                              hipStream_t stream) {
  const float* q = (const float*)d_in[0];
  const float* k = (const float*)d_in[1];
  const float* v = (const float*)d_in[2];
  const float* Wq = (const float*)d_in[3];
  const float* Wk = (const float*)d_in[4];
  const float* Wv = (const float*)d_in[5];
  const float* Wo = (const float*)d_in[6];
  const float* lnw = (const float*)d_in[7];
  float* out = (float*)d_out;
  char* ws = (char*)d_ws;

  const size_t WB = (size_t)EMB * EMB * 2;       // 8 MB  (bf16 weight)
  const size_t XB = (size_t)TSEQ * EMB * 2;      // 16 MB (bf16 activation)
  unsigned short* Wq_b = (unsigned short*)(ws + 0 * WB);
  unsigned short* Wk_b = (unsigned short*)(ws + 1 * WB);
  unsigned short* Wv_b = (unsigned short*)(ws + 2 * WB);
  unsigned short* Wo_b = (unsigned short*)(ws + 3 * WB);
  unsigned short* qb   = (unsigned short*)(ws + 4 * WB);
  unsigned short* kb   = (unsigned short*)(ws + 4 * WB + XB);
  unsigned short* vb   = (unsigned short*)(ws + 4 * WB + 2 * XB);
  unsigned short* Qb   = (unsigned short*)(ws + 4 * WB + 3 * XB);
  unsigned short* Kb   = (unsigned short*)(ws + 4 * WB + 4 * XB);
  unsigned short* Vtb  = (unsigned short*)(ws + 4 * WB + 5 * XB);
  unsigned short* yb   = qb;                         // reuse (qb dead after QKV proj)
  unsigned short* slots = (unsigned short*)(ws + 4 * WB + XB);                       // 24 MB
  float* lbuf = (float*)(ws + 4 * WB + XB + (size_t)768 * 128 * 128 * 2);            // 393 KB
  float* y2 = (float*)(ws + 4 * WB + XB);            // fp32 gemm_o out (overwrites slots after merge)

  cvt_all<<<20480, 256, 0, stream>>>(q, k, v, Wq, Wk, Wv, Wo,
                                     qb, kb, vb, Wq_b, Wk_b, Wv_b, Wo_b);

  gemm_qkv<<<384, 512, 0, stream>>>(qb, kb, vb, Wq_b, Wk_b, Wv_b, Qb, Kb, Vtb);

  attn_kernel<<<512, 256, 0, stream>>>(Qb, Kb, Vtb, slots, lbuf);

  merge_kernel<<<512, 256, 0, stream>>>(slots, lbuf, yb);

  gemm_o<<<128, 512, 0, stream>>>(yb, Wo_b, y2);

  ln_kernel<<<TSEQ, 256, 0, stream>>>(y2, q, lnw, out);
}

// Round 11
// 329.022 us; speedup vs baseline: 1.5351x; 1.5351x over previous
//
#include <hip/hip_runtime.h>

typedef __bf16 bf16x8 __attribute__((ext_vector_type(8)));
typedef __bf16 bf16x2_t __attribute__((ext_vector_type(2)));
typedef float f32x4 __attribute__((ext_vector_type(4)));
typedef float f32x16 __attribute__((ext_vector_type(16)));
typedef unsigned int u32x4 __attribute__((ext_vector_type(4)));
typedef unsigned short u16x8 __attribute__((ext_vector_type(8)));

#define EMB 2048
#define NH 16
#define HD 128
#define TSEQ 4096

// ---------- helpers ----------
__device__ __forceinline__ unsigned short f2bf(float x) {
  unsigned int u = __builtin_bit_cast(unsigned int, x);
  u += 0x7fffu + ((u >> 16) & 1u);   // RNE
  return (unsigned short)(u >> 16);
}

__device__ __forceinline__ float bf2f(unsigned short u) {
  unsigned int x = ((unsigned int)u) << 16;
  return __builtin_bit_cast(float, x);
}

__device__ __forceinline__ float ex2(float x) { return __builtin_amdgcn_exp2f(x); }

__device__ __forceinline__ void gl_lds16(const void* g, void* l) {
  __builtin_amdgcn_global_load_lds((__attribute__((address_space(1))) void*)(void*)g,
                                   (__attribute__((address_space(3))) void*)l, 16, 0, 0);
}

template <typename OutT>
__device__ __forceinline__ void store_out(OutT* p, float v) {
  if constexpr (sizeof(OutT) == 2) { *p = f2bf(v); } else { *p = v; }
}

// ---------- fused fp32 -> bf16 convert for all 7 tensors ----------
__global__ __launch_bounds__(256) void cvt_all(const float* __restrict__ q, const float* __restrict__ k,
                                               const float* __restrict__ v, const float* __restrict__ Wq,
                                               const float* __restrict__ Wk, const float* __restrict__ Wv,
                                               const float* __restrict__ Wo,
                                               unsigned short* qb, unsigned short* kb, unsigned short* vb,
                                               unsigned short* Wqb, unsigned short* Wkb, unsigned short* Wvb,
                                               unsigned short* Wob) {
  const int SX = TSEQ * EMB / 8;   // 2^20
  const int SW = EMB * EMB / 8;    // 2^19
  int i = blockIdx.x * 256 + threadIdx.x;
  const float* src; unsigned short* dst; int off;
  if (i < 3 * SX) {
    int seg = i >> 20; off = i & (SX - 1);
    src = (seg == 0) ? q : (seg == 1) ? k : v;
    dst = (seg == 0) ? qb : (seg == 1) ? kb : vb;
  } else {
    int j = i - 3 * SX;
    int seg = j >> 19; off = j & (SW - 1);
    src = (seg == 0) ? Wq : (seg == 1) ? Wk : (seg == 2) ? Wv : Wo;
    dst = (seg == 0) ? Wqb : (seg == 1) ? Wkb : (seg == 2) ? Wvb : Wob;
  }
  const float4* p = (const float4*)src + (size_t)off * 2;
  float4 a = p[0], b = p[1];
  u32x4 r;
  r.x = (unsigned)f2bf(a.x) | ((unsigned)f2bf(a.y) << 16);
  r.y = (unsigned)f2bf(a.z) | ((unsigned)f2bf(a.w) << 16);
  r.z = (unsigned)f2bf(b.x) | ((unsigned)f2bf(b.y) << 16);
  r.w = (unsigned)f2bf(b.z) | ((unsigned)f2bf(b.w) << 16);
  ((u32x4*)dst)[off] = r;
}

// ---------- NT GEMM body: C[M,N] = A[M,K] * B[N,K]^T  (128x128 tile, BK=32) ----------
// r8's proven staging/sync structure (counted-vmcnt double-buffer, both-side swizzle).
template <typename OutT>
__device__ __forceinline__ void gemm_body(const unsigned short* __restrict__ A,
                                          const unsigned short* __restrict__ B,
                                          OutT* __restrict__ C,
                                          int m0, int n0, int N, int K, char* smem, float oscale) {
  const int t = threadIdx.x;
  const int l = t & 63, lg = l >> 4, l15 = l & 15;
  const int w = t >> 6, wm = w >> 1, wn = w & 1;

  f32x4 acc[4][4] = {};

  const int rowS = t >> 2;
  const int cbS = (t & 3) * 16;
  const int swS = cbS ^ ((rowS & 3) << 4);        // pre-swizzled source column byte
  const char* Ab = (const char*)A + ((size_t)(m0 + rowS) * K) * 2;
  const char* Bb = (const char*)B + ((size_t)(n0 + rowS) * K) * 2;
  const size_t rowStep = (size_t)64 * K * 2;

  auto stage = [&](int buf, int kt) {
    const int ktB = kt * 2;
    char* sA = smem + buf * 8192;
    char* sB = smem + 16384 + buf * 8192;
    gl_lds16(Ab + ktB + swS, sA + t * 16);
    gl_lds16(Ab + rowStep + ktB + swS, sA + 4096 + t * 16);   // (row+64)&3 == row&3
    gl_lds16(Bb + ktB + swS, sB + t * 16);
    gl_lds16(Bb + rowStep + ktB + swS, sB + 4096 + t * 16);
  };

  const int nIter = K / 32;
  stage(0, 0);
  int cur = 0;
  for (int it = 0; it < nIter; ++it) {
    if (it + 1 < nIter) {
      stage(cur ^ 1, (it + 1) * 32);
      asm volatile("s_waitcnt vmcnt(4)" ::: "memory");   // wait only for CURRENT tile's stage
    } else {
      asm volatile("s_waitcnt vmcnt(0)" ::: "memory");
    }
    __builtin_amdgcn_s_barrier();

    const char* sA = smem + cur * 8192;
    const char* sB = smem + 16384 + cur * 8192;
    const int rsw = (l15 & 3) << 4;                      // read-side XOR (rows mod 4 = l15&3)
    bf16x8 af[4], bfr[4];
#pragma unroll
    for (int m = 0; m < 4; m++) {
      const int r = wm * 64 + m * 16 + l15;
      af[m] = *(const bf16x8*)(sA + r * 64 + ((lg * 16) ^ rsw));
    }
#pragma unroll
    for (int n = 0; n < 4; n++) {
      const int r = wn * 64 + n * 16 + l15;
      bfr[n] = *(const bf16x8*)(sB + r * 64 + ((lg * 16) ^ rsw));
    }
#pragma unroll
    for (int m = 0; m < 4; m++)
#pragma unroll
      for (int n = 0; n < 4; n++)
        acc[m][n] = __builtin_amdgcn_mfma_f32_16x16x32_bf16(af[m], bfr[n], acc[m][n], 0, 0, 0);

    __builtin_amdgcn_s_barrier();   // all waves done reading buf[cur] before it is restaged
    cur ^= 1;
  }

#pragma unroll
  for (int m = 0; m < 4; m++) {
    int row = m0 + wm * 64 + m * 16 + 4 * lg;
#pragma unroll
    for (int n = 0; n < 4; n++) {
      int col = n0 + wn * 64 + n * 16 + l15;
#pragma unroll
      for (int i = 0; i < 4; i++)
        store_out(C + (size_t)(row + i) * N + col, acc[m][n][i] * oscale);
    }
  }
}

// Fused Q/K/V projections: 1536 blocks, XCD-bijective chunked swizzle (1536 % 8 == 0).
// Consecutive wg (same A-panel) land on the same XCD -> L2 reuse of A rows.
// Q output pre-scaled by 1/sqrt(HD)*log2(e) so attention softmax runs in exp2 domain.
__global__ __launch_bounds__(256) void gemm_qkv(const unsigned short* __restrict__ qb,
                                                const unsigned short* __restrict__ kb,
                                                const unsigned short* __restrict__ vb,
                                                const unsigned short* __restrict__ Wq,
                                                const unsigned short* __restrict__ Wk,
                                                const unsigned short* __restrict__ Wv,
                                                unsigned short* Qo, unsigned short* Ko, unsigned short* Vto) {
  __shared__ char smem[32768];
  const int bx = blockIdx.x;
  const int wg = (bx & 7) * 192 + (bx >> 3);   // XCD chunking, bijective
  const int z = wg >> 9, r = wg & 511;
  const unsigned short* A; const unsigned short* B; unsigned short* C;
  int N, m0, n0; float sc;
  if (z == 0)      { A = qb; B = Wq; C = Qo;  N = EMB;  n0 = (r & 15) << 7; m0 = (r >> 4) << 7; sc = 0.12751743f; }
  else if (z == 1) { A = kb; B = Wk; C = Ko;  N = EMB;  n0 = (r & 15) << 7; m0 = (r >> 4) << 7; sc = 1.0f; }
  else             { A = Wv; B = vb; C = Vto; N = TSEQ; n0 = (r & 31) << 7; m0 = (r >> 5) << 7; sc = 1.0f; }
  gemm_body<unsigned short>(A, B, C, m0, n0, N, EMB, smem, sc);
}

// Output projection -> bf16 y2 (halves y2 traffic; LN reads bf16).
__global__ __launch_bounds__(256) void gemm_o(const unsigned short* __restrict__ A,
                                              const unsigned short* __restrict__ B,
                                              unsigned short* __restrict__ C) {
  __shared__ char smem[32768];
  const int bx = blockIdx.x;
  const int wg = (bx & 7) * 64 + (bx >> 3);    // 512 blocks, XCD-bijective
  gemm_body<unsigned short>(A, B, C, (wg >> 4) * 128, (wg & 15) * 128, EMB, EMB, smem, 1.0f);
}

// ---------- flash attention (causal), swapped-QK^T, 32x32x16 MFMA, static-max softmax ----------
// 512 UNIFORM blocks of exactly 33 kv-iterations each (kv-split pairing, see r5).
__global__ __launch_bounds__(256, 2) void attn_kernel(const unsigned short* __restrict__ Q,
                                                      const unsigned short* __restrict__ Kp,
                                                      const unsigned short* __restrict__ Vt,
                                                      unsigned short* __restrict__ slots,
                                                      float* __restrict__ lbuf) {
  __shared__ char sK[2][16384];  // [64 kv][128 hd] bf16, 256B rows, xor-swz (&15)
  __shared__ char sV[3][16384];  // [128 hd][64 kv] bf16, 128B rows, xor-swz (&7)
  const int t = threadIdx.x, l = t & 63, w = t >> 6;
  const int l31 = l & 31, hh = l >> 5;
  const int b = blockIdx.x;
  const int h = b >> 5;
  const int p = (b >> 1) & 15;
  const int half = b & 1;
  const int slotBase = (h * 16 + p) * 3;

  const int q0A = 128 * p, q0B = 128 * (31 - p);
  const int swi = (half == 0) ? (2 * p + 2) : 64;   // gi at which tile B starts (64 = never)
  const int kvOff = 31 - 2 * p;                     // half-1 kv-block offset

  int q0 = (half == 0) ? q0A : q0B;
  int qrow = q0 + w * 32 + l31;

  auto kvof = [&](int gi) -> int {
    if (half == 0) return (gi < swi) ? gi * 64 : (gi - swi) * 64;
    return (kvOff + gi) * 64;
  };

  bf16x8 qf[8];
#pragma unroll
  for (int kd = 0; kd < 8; kd++)
    qf[kd] = *(const bf16x8*)(Q + (size_t)qrow * EMB + h * HD + kd * 16 + hh * 8);

  f32x16 o[4] = {};
  float l_run = 0.0f;

  const int rK = t >> 4, cK = (t & 15) * 16;
  const int rV = t >> 3, cV = (t & 7) * 16;
  const char* Kb = (const char*)Kp;
  const char* Vb = (const char*)Vt;

  auto stage = [&](int kbuf, int vbuf, int kv0) {
#pragma unroll
    for (int c = 0; c < 4; c++) {
      int rowK = c * 16 + rK;
      gl_lds16(Kb + (size_t)(kv0 + rowK) * (EMB * 2) + h * (HD * 2) + (cK ^ ((rowK & 15) << 4)),
               sK[kbuf] + c * 4096 + t * 16);
      int rowV = c * 32 + rV;
      gl_lds16(Vb + (size_t)(h * HD + rowV) * (TSEQ * 2) + kv0 * 2 + (cV ^ ((rowV & 7) << 4)),
               sV[vbuf] + c * 4096 + t * 16);
    }
  };

  auto writeout = [&](int slotId) {
    unsigned short* S = slots + (size_t)slotId * (128 * 128);
    const int r = w * 32 + l31;
    float lt = l_run + __shfl_xor(l_run, 32, 64);
    if (hh == 0) lbuf[slotId * 128 + r] = lt;
#pragma unroll
    for (int hdm = 0; hdm < 4; hdm++)
#pragma unroll
      for (int rq = 0; rq < 4; rq++) {
        ushort4 st;
        st.x = f2bf(o[hdm][4 * rq + 0]);
        st.y = f2bf(o[hdm][4 * rq + 1]);
        st.z = f2bf(o[hdm][4 * rq + 2]);
        st.w = f2bf(o[hdm][4 * rq + 3]);
        *(ushort4*)(S + r * 128 + hdm * 32 + 8 * rq + 4 * hh) = st;
      }
  };

  stage(0, 0, kvof(0));
  int kc = 0, vc = 0, vn = 1;
  for (int gi = 0; gi < 33; ++gi) {
    if (half == 0 && gi == swi) {
      writeout(slotBase + 0);
#pragma unroll
      for (int hdm = 0; hdm < 4; hdm++)
#pragma unroll
        for (int i = 0; i < 16; i++) o[hdm][i] = 0.0f;
      l_run = 0.0f;
      q0 = q0B;
      qrow = q0 + w * 32 + l31;
#pragma unroll
      for (int kd = 0; kd < 8; kd++)
        qf[kd] = *(const bf16x8*)(Q + (size_t)qrow * EMB + h * HD + kd * 16 + hh * 8);
    }
    const int kv0 = kvof(gi);
    if (gi + 1 < 33) {
      stage(kc ^ 1, vn, kvof(gi + 1));
      asm volatile("s_waitcnt vmcnt(8)" ::: "memory");
    } else {
      asm volatile("s_waitcnt vmcnt(0)" ::: "memory");
    }
    __builtin_amdgcn_s_barrier();

    const char* KB = sK[kc];
    const char* VB = sV[vc];

    f32x16 s[2];
#pragma unroll
    for (int i = 0; i < 16; i++) { s[0][i] = -8.0f; s[1][i] = -8.0f; }
    __builtin_amdgcn_s_setprio(1);
#pragma unroll
    for (int kvm = 0; kvm < 2; kvm++) {
      const int rowA = kvm * 32 + l31;
      const int swz = (rowA & 15) << 4;
#pragma unroll
      for (int kd = 0; kd < 8; kd++) {
        bf16x8 kf = *(const bf16x8*)(KB + rowA * 256 + ((kd * 32 + hh * 16) ^ swz));
        s[kvm] = __builtin_amdgcn_mfma_f32_32x32x16_bf16(kf, qf[kd], s[kvm], 0, 0, 0);
      }
    }
    __builtin_amdgcn_s_setprio(0);
    __builtin_amdgcn_s_barrier();

    const bool diag = (kv0 + 64 > q0);
    if (diag) {
#pragma unroll
      for (int kvm = 0; kvm < 2; kvm++)
#pragma unroll
        for (int i = 0; i < 16; i++)
          if (kv0 + kvm * 32 + (i & 3) + 8 * (i >> 2) + 4 * hh > qrow) s[kvm][i] = -1e30f;
    }
    float psum = 0.0f;
    unsigned int wb[16];
#pragma unroll
    for (int kvm = 0; kvm < 2; kvm++)
#pragma unroll
      for (int m = 0; m < 8; m++) {
        float p0 = ex2(s[kvm][2 * m + 0]);
        float p1 = ex2(s[kvm][2 * m + 1]);
        psum += p0 + p1;
        bf16x2_t pk; pk[0] = (__bf16)p0; pk[1] = (__bf16)p1;
        wb[kvm * 8 + m] = __builtin_bit_cast(unsigned int, pk);
      }
    l_run += psum;

    __builtin_amdgcn_s_setprio(1);
#pragma unroll
    for (int kvm = 0; kvm < 2; kvm++)
#pragma unroll
      for (int sx = 0; sx < 2; sx++) {
        const int base = kvm * 8 + 4 * sx;
        const unsigned int a0 = wb[base + 0], a1 = wb[base + 1];
        const unsigned int b0 = wb[base + 2], b1 = wb[base + 3];
        const unsigned int snd0 = hh ? a0 : b0;
        const unsigned int snd1 = hh ? a1 : b1;
        const unsigned int rcv0 = (unsigned int)__shfl_xor((int)snd0, 32, 64);
        const unsigned int rcv1 = (unsigned int)__shfl_xor((int)snd1, 32, 64);
        u32x4 pw;
        pw.x = hh ? rcv0 : a0;
        pw.y = hh ? rcv1 : a1;
        pw.z = hh ? b0 : rcv0;
        pw.w = hh ? b1 : rcv1;
        const bf16x8 pfrag = __builtin_bit_cast(bf16x8, pw);
        const int ks = kvm * 2 + sx;
#pragma unroll
        for (int hdm = 0; hdm < 4; hdm++) {
          const int rowA = hdm * 32 + l31;
          bf16x8 vf = *(const bf16x8*)(VB + rowA * 128 + ((ks * 32 + hh * 16) ^ ((rowA & 7) << 4)));
          o[hdm] = __builtin_amdgcn_mfma_f32_32x32x16_bf16(vf, pfrag, o[hdm], 0, 0, 0);
        }
      }
    __builtin_amdgcn_s_setprio(0);

    kc ^= 1;
    vc = vn;
    vn = (vn == 2) ? 0 : vn + 1;
  }

  writeout(slotBase + ((half == 0) ? 1 : 2));
}

// ---------- merge partials -> normalized bf16 y ----------
__global__ __launch_bounds__(256) void merge_kernel(const unsigned short* __restrict__ slots,
                                                    const float* __restrict__ lbuf,
                                                    unsigned short* __restrict__ Y) {
  const int tile = blockIdx.x;
  const int h = tile >> 5, tt = tile & 31;
  const int p = (tt <= 15) ? tt : 31 - tt;
  const int base = (h * 16 + p) * 3;
  const int t = threadIdx.x;
  const int r = t >> 1;
  const int c0 = (t & 1) * 64;
  unsigned short* yp = Y + (size_t)(128 * tt + r) * EMB + h * HD + c0;
  if (tt <= 15) {
    const unsigned short* S = slots + (size_t)(base + 0) * (128 * 128) + r * 128 + c0;
    const float inv = 1.0f / lbuf[(base + 0) * 128 + r];
#pragma unroll
    for (int j = 0; j < 8; j++) {
      u16x8 a = ((const u16x8*)S)[j];
      u16x8 ov;
#pragma unroll
      for (int e = 0; e < 8; e++) ov[e] = f2bf(bf2f(a[e]) * inv);
      ((u16x8*)yp)[j] = ov;
    }
  } else {
    const unsigned short* S0 = slots + (size_t)(base + 1) * (128 * 128) + r * 128 + c0;
    const unsigned short* S1 = slots + (size_t)(base + 2) * (128 * 128) + r * 128 + c0;
    const float inv = 1.0f / (lbuf[(base + 1) * 128 + r] + lbuf[(base + 2) * 128 + r]);
#pragma unroll
    for (int j = 0; j < 8; j++) {
      u16x8 a = ((const u16x8*)S0)[j];
      u16x8 c = ((const u16x8*)S1)[j];
      u16x8 ov;
#pragma unroll
      for (int e = 0; e < 8; e++) ov[e] = f2bf((bf2f(a[e]) + bf2f(c[e])) * inv);
      ((u16x8*)yp)[j] = ov;
    }
  }
}

// ---------- residual + LayerNorm (scale only); y2 is bf16 ----------
__global__ __launch_bounds__(256) void ln_kernel(const unsigned short* __restrict__ y2,
                                                 const float* __restrict__ qin,
                                                 const float* __restrict__ lnw,
                                                 float* __restrict__ out) {
  const int row = blockIdx.x, t = threadIdx.x;
  const u16x8* Y = (const u16x8*)(y2 + (size_t)row * EMB);
  const float4* Qv = (const float4*)(qin + (size_t)row * EMB);
  u16x8 yv = Y[t];
  float4 b0 = Qv[2 * t], b1 = Qv[2 * t + 1];
  float x[8];
  x[0] = bf2f(yv[0]) + b0.x; x[1] = bf2f(yv[1]) + b0.y;
  x[2] = bf2f(yv[2]) + b0.z; x[3] = bf2f(yv[3]) + b0.w;
  x[4] = bf2f(yv[4]) + b1.x; x[5] = bf2f(yv[5]) + b1.y;
  x[6] = bf2f(yv[6]) + b1.z; x[7] = bf2f(yv[7]) + b1.w;
  float s = 0.0f, s2 = 0.0f;
#pragma unroll
  for (int j = 0; j < 8; j++) { s += x[j]; s2 += x[j] * x[j]; }
#pragma unroll
  for (int d = 1; d < 64; d <<= 1) {
    s += __shfl_xor(s, d, 64);
    s2 += __shfl_xor(s2, d, 64);
  }
  __shared__ float red[8];
  if ((t & 63) == 0) { red[(t >> 6) * 2] = s; red[(t >> 6) * 2 + 1] = s2; }
  __syncthreads();
  s = red[0] + red[2] + red[4] + red[6];
  s2 = red[1] + red[3] + red[5] + red[7];
  float mu = s * (1.0f / EMB);
  float var = s2 * (1.0f / EMB) - mu * mu;
  float r = rsqrtf(var + 1e-5f);
  const float4* Wv4 = (const float4*)lnw;
  float4 w0 = Wv4[2 * t], w1 = Wv4[2 * t + 1];
  float4 o0, o1;
  o0.x = (x[0] - mu) * r * w0.x; o0.y = (x[1] - mu) * r * w0.y;
  o0.z = (x[2] - mu) * r * w0.z; o0.w = (x[3] - mu) * r * w0.w;
  o1.x = (x[4] - mu) * r * w1.x; o1.y = (x[5] - mu) * r * w1.y;
  o1.z = (x[6] - mu) * r * w1.z; o1.w = (x[7] - mu) * r * w1.w;
  ((float4*)(out + (size_t)row * EMB))[2 * t] = o0;
  ((float4*)(out + (size_t)row * EMB))[2 * t + 1] = o1;
}

// ---------- launch ----------
extern "C" void kernel_launch(void* const* d_in, const int* in_sizes, int n_in,
                              void* d_out, int out_size, void* d_ws, size_t ws_size,
                              hipStream_t stream) {
  const float* q = (const float*)d_in[0];
  const float* k = (const float*)d_in[1];
  const float* v = (const float*)d_in[2];
  const float* Wq = (const float*)d_in[3];
  const float* Wk = (const float*)d_in[4];
  const float* Wv = (const float*)d_in[5];
  const float* Wo = (const float*)d_in[6];
  const float* lnw = (const float*)d_in[7];
  float* out = (float*)d_out;
  char* ws = (char*)d_ws;

  const size_t WB = (size_t)EMB * EMB * 2;       // 8 MB  (bf16 weight)
  const size_t XB = (size_t)TSEQ * EMB * 2;      // 16 MB (bf16 activation)
  unsigned short* Wq_b = (unsigned short*)(ws + 0 * WB);
  unsigned short* Wk_b = (unsigned short*)(ws + 1 * WB);
  unsigned short* Wv_b = (unsigned short*)(ws + 2 * WB);
  unsigned short* Wo_b = (unsigned short*)(ws + 3 * WB);
  unsigned short* qb   = (unsigned short*)(ws + 4 * WB);
  unsigned short* kb   = (unsigned short*)(ws + 4 * WB + XB);
  unsigned short* vb   = (unsigned short*)(ws + 4 * WB + 2 * XB);
  unsigned short* Qb   = (unsigned short*)(ws + 4 * WB + 3 * XB);
  unsigned short* Kb   = (unsigned short*)(ws + 4 * WB + 4 * XB);
  unsigned short* Vtb  = (unsigned short*)(ws + 4 * WB + 5 * XB);
  unsigned short* yb   = qb;                         // reuse (qb dead after QKV proj)
  unsigned short* slots = (unsigned short*)(ws + 4 * WB + XB);                       // 24 MB
  float* lbuf = (float*)(ws + 4 * WB + XB + (size_t)768 * 128 * 128 * 2);            // 393 KB
  unsigned short* y2 = (unsigned short*)(ws + 4 * WB + XB);   // bf16 gemm_o out (over slots, post-merge)

  cvt_all<<<20480, 256, 0, stream>>>(q, k, v, Wq, Wk, Wv, Wo,
                                     qb, kb, vb, Wq_b, Wk_b, Wv_b, Wo_b);

  gemm_qkv<<<1536, 256, 0, stream>>>(qb, kb, vb, Wq_b, Wk_b, Wv_b, Qb, Kb, Vtb);

  attn_kernel<<<512, 256, 0, stream>>>(Qb, Kb, Vtb, slots, lbuf);

  merge_kernel<<<512, 256, 0, stream>>>(slots, lbuf, yb);

  gemm_o<<<512, 256, 0, stream>>>(yb, Wo_b, y2);

  ln_kernel<<<TSEQ, 256, 0, stream>>>(y2, q, lnw, out);
}

// Round 12
// 324.420 us; speedup vs baseline: 1.5568x; 1.0142x over previous
//
#include <hip/hip_runtime.h>

typedef __bf16 bf16x8 __attribute__((ext_vector_type(8)));
typedef __bf16 bf16x2_t __attribute__((ext_vector_type(2)));
typedef float f32x4 __attribute__((ext_vector_type(4)));
typedef float f32x16 __attribute__((ext_vector_type(16)));
typedef unsigned int u32x4 __attribute__((ext_vector_type(4)));
typedef unsigned short u16x8 __attribute__((ext_vector_type(8)));

#define EMB 2048
#define NH 16
#define HD 128
#define TSEQ 4096

// ---------- helpers ----------
__device__ __forceinline__ unsigned short f2bf(float x) {
  unsigned int u = __builtin_bit_cast(unsigned int, x);
  u += 0x7fffu + ((u >> 16) & 1u);   // RNE
  return (unsigned short)(u >> 16);
}

__device__ __forceinline__ float bf2f(unsigned short u) {
  unsigned int x = ((unsigned int)u) << 16;
  return __builtin_bit_cast(float, x);
}

__device__ __forceinline__ float ex2(float x) { return __builtin_amdgcn_exp2f(x); }

__device__ __forceinline__ void gl_lds16(const void* g, void* l) {
  __builtin_amdgcn_global_load_lds((__attribute__((address_space(1))) void*)(void*)g,
                                   (__attribute__((address_space(3))) void*)l, 16, 0, 0);
}

template <typename OutT>
__device__ __forceinline__ void store_out(OutT* p, float v) {
  if constexpr (sizeof(OutT) == 2) { *p = f2bf(v); } else { *p = v; }
}

// ---------- fused fp32 -> bf16 convert for all 7 tensors ----------
__global__ __launch_bounds__(256) void cvt_all(const float* __restrict__ q, const float* __restrict__ k,
                                               const float* __restrict__ v, const float* __restrict__ Wq,
                                               const float* __restrict__ Wk, const float* __restrict__ Wv,
                                               const float* __restrict__ Wo,
                                               unsigned short* qb, unsigned short* kb, unsigned short* vb,
                                               unsigned short* Wqb, unsigned short* Wkb, unsigned short* Wvb,
                                               unsigned short* Wob) {
  const int SX = TSEQ * EMB / 8;   // 2^20
  const int SW = EMB * EMB / 8;    // 2^19
  int i = blockIdx.x * 256 + threadIdx.x;
  const float* src; unsigned short* dst; int off;
  if (i < 3 * SX) {
    int seg = i >> 20; off = i & (SX - 1);
    src = (seg == 0) ? q : (seg == 1) ? k : v;
    dst = (seg == 0) ? qb : (seg == 1) ? kb : vb;
  } else {
    int j = i - 3 * SX;
    int seg = j >> 19; off = j & (SW - 1);
    src = (seg == 0) ? Wq : (seg == 1) ? Wk : (seg == 2) ? Wv : Wo;
    dst = (seg == 0) ? Wqb : (seg == 1) ? Wkb : (seg == 2) ? Wvb : Wob;
  }
  const float4* p = (const float4*)src + (size_t)off * 2;
  float4 a = p[0], b = p[1];
  u32x4 r;
  r.x = (unsigned)f2bf(a.x) | ((unsigned)f2bf(a.y) << 16);
  r.y = (unsigned)f2bf(a.z) | ((unsigned)f2bf(a.w) << 16);
  r.z = (unsigned)f2bf(b.x) | ((unsigned)f2bf(b.y) << 16);
  r.w = (unsigned)f2bf(b.z) | ((unsigned)f2bf(b.w) << 16);
  ((u32x4*)dst)[off] = r;
}

// ---------- NT GEMM body: C[M,N] = A[M,K] * B[N,K]^T  (128x128 tile, BK=32) ----------
// r8's proven staging/sync structure (counted-vmcnt double-buffer, both-side swizzle).
template <typename OutT>
__device__ __forceinline__ void gemm_body(const unsigned short* __restrict__ A,
                                          const unsigned short* __restrict__ B,
                                          OutT* __restrict__ C,
                                          int m0, int n0, int N, int K, char* smem, float oscale) {
  const int t = threadIdx.x;
  const int l = t & 63, lg = l >> 4, l15 = l & 15;
  const int w = t >> 6, wm = w >> 1, wn = w & 1;

  f32x4 acc[4][4] = {};

  const int rowS = t >> 2;
  const int cbS = (t & 3) * 16;
  const int swS = cbS ^ ((rowS & 3) << 4);        // pre-swizzled source column byte
  const char* Ab = (const char*)A + ((size_t)(m0 + rowS) * K) * 2;
  const char* Bb = (const char*)B + ((size_t)(n0 + rowS) * K) * 2;
  const size_t rowStep = (size_t)64 * K * 2;

  auto stage = [&](int buf, int kt) {
    const int ktB = kt * 2;
    char* sA = smem + buf * 8192;
    char* sB = smem + 16384 + buf * 8192;
    gl_lds16(Ab + ktB + swS, sA + t * 16);
    gl_lds16(Ab + rowStep + ktB + swS, sA + 4096 + t * 16);   // (row+64)&3 == row&3
    gl_lds16(Bb + ktB + swS, sB + t * 16);
    gl_lds16(Bb + rowStep + ktB + swS, sB + 4096 + t * 16);
  };

  const int nIter = K / 32;
  stage(0, 0);
  int cur = 0;
  for (int it = 0; it < nIter; ++it) {
    if (it + 1 < nIter) {
      stage(cur ^ 1, (it + 1) * 32);
      asm volatile("s_waitcnt vmcnt(4)" ::: "memory");   // wait only for CURRENT tile's stage
    } else {
      asm volatile("s_waitcnt vmcnt(0)" ::: "memory");
    }
    __builtin_amdgcn_s_barrier();

    const char* sA = smem + cur * 8192;
    const char* sB = smem + 16384 + cur * 8192;
    const int rsw = (l15 & 3) << 4;                      // read-side XOR (rows mod 4 = l15&3)
    bf16x8 af[4], bfr[4];
#pragma unroll
    for (int m = 0; m < 4; m++) {
      const int r = wm * 64 + m * 16 + l15;
      af[m] = *(const bf16x8*)(sA + r * 64 + ((lg * 16) ^ rsw));
    }
#pragma unroll
    for (int n = 0; n < 4; n++) {
      const int r = wn * 64 + n * 16 + l15;
      bfr[n] = *(const bf16x8*)(sB + r * 64 + ((lg * 16) ^ rsw));
    }
#pragma unroll
    for (int m = 0; m < 4; m++)
#pragma unroll
      for (int n = 0; n < 4; n++)
        acc[m][n] = __builtin_amdgcn_mfma_f32_16x16x32_bf16(af[m], bfr[n], acc[m][n], 0, 0, 0);

    __builtin_amdgcn_s_barrier();   // all waves done reading buf[cur] before it is restaged
    cur ^= 1;
  }

#pragma unroll
  for (int m = 0; m < 4; m++) {
    int row = m0 + wm * 64 + m * 16 + 4 * lg;
#pragma unroll
    for (int n = 0; n < 4; n++) {
      int col = n0 + wn * 64 + n * 16 + l15;
#pragma unroll
      for (int i = 0; i < 4; i++)
        store_out(C + (size_t)(row + i) * N + col, acc[m][n][i] * oscale);
    }
  }
}

// Fused Q/K/V projections: 1536 blocks, linear grid (r8's proven mapping).
// Q output pre-scaled by 1/sqrt(HD)*log2(e) so attention softmax runs in exp2 domain.
__global__ __launch_bounds__(256) void gemm_qkv(const unsigned short* __restrict__ qb,
                                                const unsigned short* __restrict__ kb,
                                                const unsigned short* __restrict__ vb,
                                                const unsigned short* __restrict__ Wq,
                                                const unsigned short* __restrict__ Wk,
                                                const unsigned short* __restrict__ Wv,
                                                unsigned short* Qo, unsigned short* Ko, unsigned short* Vto) {
  __shared__ char smem[32768];
  const int bx = blockIdx.x;
  const int z = bx >> 9, r = bx & 511;
  const unsigned short* A; const unsigned short* B; unsigned short* C;
  int N, m0, n0; float sc;
  if (z == 0)      { A = qb; B = Wq; C = Qo;  N = EMB;  n0 = (r & 15) << 7; m0 = (r >> 4) << 7; sc = 0.12751743f; }
  else if (z == 1) { A = kb; B = Wk; C = Ko;  N = EMB;  n0 = (r & 15) << 7; m0 = (r >> 4) << 7; sc = 1.0f; }
  else             { A = Wv; B = vb; C = Vto; N = TSEQ; n0 = (r & 31) << 7; m0 = (r >> 5) << 7; sc = 1.0f; }
  gemm_body<unsigned short>(A, B, C, m0, n0, N, EMB, smem, sc);
}

// Output projection -> bf16 y2 (halves y2 traffic; LN reads bf16).
__global__ __launch_bounds__(256) void gemm_o(const unsigned short* __restrict__ A,
                                              const unsigned short* __restrict__ B,
                                              unsigned short* __restrict__ C) {
  __shared__ char smem[32768];
  gemm_body<unsigned short>(A, B, C, blockIdx.y * 128, blockIdx.x * 128, EMB, EMB, smem, 1.0f);
}

// ---------- flash attention (causal), swapped-QK^T, 32x32x16 MFMA, static-max softmax ----------
// 512 UNIFORM blocks of exactly 33 kv-iterations each (kv-split pairing, see r5).
__global__ __launch_bounds__(256, 2) void attn_kernel(const unsigned short* __restrict__ Q,
                                                      const unsigned short* __restrict__ Kp,
                                                      const unsigned short* __restrict__ Vt,
                                                      unsigned short* __restrict__ slots,
                                                      float* __restrict__ lbuf) {
  __shared__ char sK[2][16384];  // [64 kv][128 hd] bf16, 256B rows, xor-swz (&15)
  __shared__ char sV[3][16384];  // [128 hd][64 kv] bf16, 128B rows, xor-swz (&7)
  const int t = threadIdx.x, l = t & 63, w = t >> 6;
  const int l31 = l & 31, hh = l >> 5;
  const int b = blockIdx.x;
  const int h = b >> 5;
  const int p = (b >> 1) & 15;
  const int half = b & 1;
  const int slotBase = (h * 16 + p) * 3;

  const int q0A = 128 * p, q0B = 128 * (31 - p);
  const int swi = (half == 0) ? (2 * p + 2) : 64;   // gi at which tile B starts (64 = never)
  const int kvOff = 31 - 2 * p;                     // half-1 kv-block offset

  int q0 = (half == 0) ? q0A : q0B;
  int qrow = q0 + w * 32 + l31;

  auto kvof = [&](int gi) -> int {
    if (half == 0) return (gi < swi) ? gi * 64 : (gi - swi) * 64;
    return (kvOff + gi) * 64;
  };

  bf16x8 qf[8];
#pragma unroll
  for (int kd = 0; kd < 8; kd++)
    qf[kd] = *(const bf16x8*)(Q + (size_t)qrow * EMB + h * HD + kd * 16 + hh * 8);

  f32x16 o[4] = {};
  float l_run = 0.0f;

  const int rK = t >> 4, cK = (t & 15) * 16;
  const int rV = t >> 3, cV = (t & 7) * 16;
  const char* Kb = (const char*)Kp;
  const char* Vb = (const char*)Vt;

  auto stage = [&](int kbuf, int vbuf, int kv0) {
#pragma unroll
    for (int c = 0; c < 4; c++) {
      int rowK = c * 16 + rK;
      gl_lds16(Kb + (size_t)(kv0 + rowK) * (EMB * 2) + h * (HD * 2) + (cK ^ ((rowK & 15) << 4)),
               sK[kbuf] + c * 4096 + t * 16);
      int rowV = c * 32 + rV;
      gl_lds16(Vb + (size_t)(h * HD + rowV) * (TSEQ * 2) + kv0 * 2 + (cV ^ ((rowV & 7) << 4)),
               sV[vbuf] + c * 4096 + t * 16);
    }
  };

  auto writeout = [&](int slotId) {
    unsigned short* S = slots + (size_t)slotId * (128 * 128);
    const int r = w * 32 + l31;
    float lt = l_run + __shfl_xor(l_run, 32, 64);
    if (hh == 0) lbuf[slotId * 128 + r] = lt;
#pragma unroll
    for (int hdm = 0; hdm < 4; hdm++)
#pragma unroll
      for (int rq = 0; rq < 4; rq++) {
        ushort4 st;
        st.x = f2bf(o[hdm][4 * rq + 0]);
        st.y = f2bf(o[hdm][4 * rq + 1]);
        st.z = f2bf(o[hdm][4 * rq + 2]);
        st.w = f2bf(o[hdm][4 * rq + 3]);
        *(ushort4*)(S + r * 128 + hdm * 32 + 8 * rq + 4 * hh) = st;
      }
  };

  stage(0, 0, kvof(0));
  int kc = 0, vc = 0, vn = 1;
  for (int gi = 0; gi < 33; ++gi) {
    if (half == 0 && gi == swi) {
      writeout(slotBase + 0);
#pragma unroll
      for (int hdm = 0; hdm < 4; hdm++)
#pragma unroll
        for (int i = 0; i < 16; i++) o[hdm][i] = 0.0f;
      l_run = 0.0f;
      q0 = q0B;
      qrow = q0 + w * 32 + l31;
#pragma unroll
      for (int kd = 0; kd < 8; kd++)
        qf[kd] = *(const bf16x8*)(Q + (size_t)qrow * EMB + h * HD + kd * 16 + hh * 8);
    }
    const int kv0 = kvof(gi);
    if (gi + 1 < 33) {
      stage(kc ^ 1, vn, kvof(gi + 1));
      asm volatile("s_waitcnt vmcnt(8)" ::: "memory");
    } else {
      asm volatile("s_waitcnt vmcnt(0)" ::: "memory");
    }
    __builtin_amdgcn_s_barrier();

    const char* KB = sK[kc];
    const char* VB = sV[vc];

    f32x16 s[2];
#pragma unroll
    for (int i = 0; i < 16; i++) { s[0][i] = -8.0f; s[1][i] = -8.0f; }
    __builtin_amdgcn_s_setprio(1);
#pragma unroll
    for (int kvm = 0; kvm < 2; kvm++) {
      const int rowA = kvm * 32 + l31;
      const int swz = (rowA & 15) << 4;
#pragma unroll
      for (int kd = 0; kd < 8; kd++) {
        bf16x8 kf = *(const bf16x8*)(KB + rowA * 256 + ((kd * 32 + hh * 16) ^ swz));
        s[kvm] = __builtin_amdgcn_mfma_f32_32x32x16_bf16(kf, qf[kd], s[kvm], 0, 0, 0);
      }
    }
    __builtin_amdgcn_s_setprio(0);
    __builtin_amdgcn_s_barrier();

    const bool diag = (kv0 + 64 > q0);
    if (diag) {
#pragma unroll
      for (int kvm = 0; kvm < 2; kvm++)
#pragma unroll
        for (int i = 0; i < 16; i++)
          if (kv0 + kvm * 32 + (i & 3) + 8 * (i >> 2) + 4 * hh > qrow) s[kvm][i] = -1e30f;
    }
    float psum = 0.0f;
    unsigned int wb[16];
#pragma unroll
    for (int kvm = 0; kvm < 2; kvm++)
#pragma unroll
      for (int m = 0; m < 8; m++) {
        float p0 = ex2(s[kvm][2 * m + 0]);
        float p1 = ex2(s[kvm][2 * m + 1]);
        psum += p0 + p1;
        bf16x2_t pk; pk[0] = (__bf16)p0; pk[1] = (__bf16)p1;
        wb[kvm * 8 + m] = __builtin_bit_cast(unsigned int, pk);
      }
    l_run += psum;

    __builtin_amdgcn_s_setprio(1);
#pragma unroll
    for (int kvm = 0; kvm < 2; kvm++)
#pragma unroll
      for (int sx = 0; sx < 2; sx++) {
        const int base = kvm * 8 + 4 * sx;
        const unsigned int a0 = wb[base + 0], a1 = wb[base + 1];
        const unsigned int b0 = wb[base + 2], b1 = wb[base + 3];
        const unsigned int snd0 = hh ? a0 : b0;
        const unsigned int snd1 = hh ? a1 : b1;
        const unsigned int rcv0 = (unsigned int)__shfl_xor((int)snd0, 32, 64);
        const unsigned int rcv1 = (unsigned int)__shfl_xor((int)snd1, 32, 64);
        u32x4 pw;
        pw.x = hh ? rcv0 : a0;
        pw.y = hh ? rcv1 : a1;
        pw.z = hh ? b0 : rcv0;
        pw.w = hh ? b1 : rcv1;
        const bf16x8 pfrag = __builtin_bit_cast(bf16x8, pw);
        const int ks = kvm * 2 + sx;
#pragma unroll
        for (int hdm = 0; hdm < 4; hdm++) {
          const int rowA = hdm * 32 + l31;
          bf16x8 vf = *(const bf16x8*)(VB + rowA * 128 + ((ks * 32 + hh * 16) ^ ((rowA & 7) << 4)));
          o[hdm] = __builtin_amdgcn_mfma_f32_32x32x16_bf16(vf, pfrag, o[hdm], 0, 0, 0);
        }
      }
    __builtin_amdgcn_s_setprio(0);

    kc ^= 1;
    vc = vn;
    vn = (vn == 2) ? 0 : vn + 1;
  }

  writeout(slotBase + ((half == 0) ? 1 : 2));
}

// ---------- merge partials -> normalized bf16 y ----------
__global__ __launch_bounds__(256) void merge_kernel(const unsigned short* __restrict__ slots,
                                                    const float* __restrict__ lbuf,
                                                    unsigned short* __restrict__ Y) {
  const int tile = blockIdx.x;
  const int h = tile >> 5, tt = tile & 31;
  const int p = (tt <= 15) ? tt : 31 - tt;
  const int base = (h * 16 + p) * 3;
  const int t = threadIdx.x;
  const int r = t >> 1;
  const int c0 = (t & 1) * 64;
  unsigned short* yp = Y + (size_t)(128 * tt + r) * EMB + h * HD + c0;
  if (tt <= 15) {
    const unsigned short* S = slots + (size_t)(base + 0) * (128 * 128) + r * 128 + c0;
    const float inv = 1.0f / lbuf[(base + 0) * 128 + r];
#pragma unroll
    for (int j = 0; j < 8; j++) {
      u16x8 a = ((const u16x8*)S)[j];
      u16x8 ov;
#pragma unroll
      for (int e = 0; e < 8; e++) ov[e] = f2bf(bf2f(a[e]) * inv);
      ((u16x8*)yp)[j] = ov;
    }
  } else {
    const unsigned short* S0 = slots + (size_t)(base + 1) * (128 * 128) + r * 128 + c0;
    const unsigned short* S1 = slots + (size_t)(base + 2) * (128 * 128) + r * 128 + c0;
    const float inv = 1.0f / (lbuf[(base + 1) * 128 + r] + lbuf[(base + 2) * 128 + r]);
#pragma unroll
    for (int j = 0; j < 8; j++) {
      u16x8 a = ((const u16x8*)S0)[j];
      u16x8 c = ((const u16x8*)S1)[j];
      u16x8 ov;
#pragma unroll
      for (int e = 0; e < 8; e++) ov[e] = f2bf((bf2f(a[e]) + bf2f(c[e])) * inv);
      ((u16x8*)yp)[j] = ov;
    }
  }
}

// ---------- residual + LayerNorm (scale only); y2 is bf16 ----------
__global__ __launch_bounds__(256) void ln_kernel(const unsigned short* __restrict__ y2,
                                                 const float* __restrict__ qin,
                                                 const float* __restrict__ lnw,
                                                 float* __restrict__ out) {
  const int row = blockIdx.x, t = threadIdx.x;
  const u16x8* Y = (const u16x8*)(y2 + (size_t)row * EMB);
  const float4* Qv = (const float4*)(qin + (size_t)row * EMB);
  u16x8 yv = Y[t];
  float4 b0 = Qv[2 * t], b1 = Qv[2 * t + 1];
  float x[8];
  x[0] = bf2f(yv[0]) + b0.x; x[1] = bf2f(yv[1]) + b0.y;
  x[2] = bf2f(yv[2]) + b0.z; x[3] = bf2f(yv[3]) + b0.w;
  x[4] = bf2f(yv[4]) + b1.x; x[5] = bf2f(yv[5]) + b1.y;
  x[6] = bf2f(yv[6]) + b1.z; x[7] = bf2f(yv[7]) + b1.w;
  float s = 0.0f, s2 = 0.0f;
#pragma unroll
  for (int j = 0; j < 8; j++) { s += x[j]; s2 += x[j] * x[j]; }
#pragma unroll
  for (int d = 1; d < 64; d <<= 1) {
    s += __shfl_xor(s, d, 64);
    s2 += __shfl_xor(s2, d, 64);
  }
  __shared__ float red[8];
  if ((t & 63) == 0) { red[(t >> 6) * 2] = s; red[(t >> 6) * 2 + 1] = s2; }
  __syncthreads();
  s = red[0] + red[2] + red[4] + red[6];
  s2 = red[1] + red[3] + red[5] + red[7];
  float mu = s * (1.0f / EMB);
  float var = s2 * (1.0f / EMB) - mu * mu;
  float r = rsqrtf(var + 1e-5f);
  const float4* Wv4 = (const float4*)lnw;
  float4 w0 = Wv4[2 * t], w1 = Wv4[2 * t + 1];
  float4 o0, o1;
  o0.x = (x[0] - mu) * r * w0.x; o0.y = (x[1] - mu) * r * w0.y;
  o0.z = (x[2] - mu) * r * w0.z; o0.w = (x[3] - mu) * r * w0.w;
  o1.x = (x[4] - mu) * r * w1.x; o1.y = (x[5] - mu) * r * w1.y;
  o1.z = (x[6] - mu) * r * w1.z; o1.w = (x[7] - mu) * r * w1.w;
  ((float4*)(out + (size_t)row * EMB))[2 * t] = o0;
  ((float4*)(out + (size_t)row * EMB))[2 * t + 1] = o1;
}

// ---------- launch ----------
extern "C" void kernel_launch(void* const* d_in, const int* in_sizes, int n_in,
                              void* d_out, int out_size, void* d_ws, size_t ws_size,
                              hipStream_t stream) {
  const float* q = (const float*)d_in[0];
  const float* k = (const float*)d_in[1];
  const float* v = (const float*)d_in[2];
  const float* Wq = (const float*)d_in[3];
  const float* Wk = (const float*)d_in[4];
  const float* Wv = (const float*)d_in[5];
  const float* Wo = (const float*)d_in[6];
  const float* lnw = (const float*)d_in[7];
  float* out = (float*)d_out;
  char* ws = (char*)d_ws;

  const size_t WB = (size_t)EMB * EMB * 2;       // 8 MB  (bf16 weight)
  const size_t XB = (size_t)TSEQ * EMB * 2;      // 16 MB (bf16 activation)
  unsigned short* Wq_b = (unsigned short*)(ws + 0 * WB);
  unsigned short* Wk_b = (unsigned short*)(ws + 1 * WB);
  unsigned short* Wv_b = (unsigned short*)(ws + 2 * WB);
  unsigned short* Wo_b = (unsigned short*)(ws + 3 * WB);
  unsigned short* qb   = (unsigned short*)(ws + 4 * WB);
  unsigned short* kb   = (unsigned short*)(ws + 4 * WB + XB);
  unsigned short* vb   = (unsigned short*)(ws + 4 * WB + 2 * XB);
  unsigned short* Qb   = (unsigned short*)(ws + 4 * WB + 3 * XB);
  unsigned short* Kb   = (unsigned short*)(ws + 4 * WB + 4 * XB);
  unsigned short* Vtb  = (unsigned short*)(ws + 4 * WB + 5 * XB);
  unsigned short* yb   = qb;                         // reuse (qb dead after QKV proj)
  unsigned short* slots = (unsigned short*)(ws + 4 * WB + XB);                       // 24 MB
  float* lbuf = (float*)(ws + 4 * WB + XB + (size_t)768 * 128 * 128 * 2);            // 393 KB
  unsigned short* y2 = (unsigned short*)(ws + 4 * WB + XB);   // bf16 gemm_o out (over slots, post-merge)

  cvt_all<<<20480, 256, 0, stream>>>(q, k, v, Wq, Wk, Wv, Wo,
                                     qb, kb, vb, Wq_b, Wk_b, Wv_b, Wo_b);

  gemm_qkv<<<1536, 256, 0, stream>>>(qb, kb, vb, Wq_b, Wk_b, Wv_b, Qb, Kb, Vtb);

  attn_kernel<<<512, 256, 0, stream>>>(Qb, Kb, Vtb, slots, lbuf);

  merge_kernel<<<512, 256, 0, stream>>>(slots, lbuf, yb);

  gemm_o<<<dim3(16, 32), 256, 0, stream>>>(yb, Wo_b, y2);

  ln_kernel<<<TSEQ, 256, 0, stream>>>(y2, q, lnw, out);
}